// Round 7
// baseline (1738.279 us; speedup 1.0000x reference)
//
#include <hip/hip_runtime.h>
#include <hip/hip_bf16.h>

#define N_NODES   50000
#define N_PAD     50048                 // ceil64
#define N_EDGES   800000
#define N_REL     16
#define N_GRAPHS  64
#define DIM       128
#define FC_DIM    256
#define N_CLASSES 16

#define NCOARSE   782                   // dst>>6 bins
#define NCH       196                   // edge chunks
#define CHSZ      4096
#define POOL_CH   64

#define NBLK_CX   27200                 // XW_TOTAL/256
#define XW_TOTAL  (N_PAD * DIM + 2 * 17 * 16384)

// ---- ws layout (bytes, 256-aligned) ----
#define WS_HG     0                     // 32768 } memset
#define WS_CNT    32768                 // 256   } region
#define MEMSET_SZ 33024
#define WS_BLKH   33024                 // 196*782*4 = 613088 -> 613376
#define WS_COFS   646400                // 3328 (783 ints)
#define WS_RTMP   649728                // 3200000
#define WS_RECS   3849728               // 3200000
#define WS_OFFSDR 7049728               // (782*1024+1)*4 -> 3203328
#define WS_X1     10253056              // 12812288
#define WS_X2     23065344              // 12812288
#define WS_AGG    35877632              // 12812288
#define WS_WB     48689920              // 1114112  (bf16 W, 2 layers x 17 x 128x128)

typedef __attribute__((ext_vector_type(8))) short bf16x8;
typedef __attribute__((ext_vector_type(4))) float f32x4;

__device__ __forceinline__ void atomAddF(float* p, float v) {
#if defined(__gfx90a__) || defined(__gfx942__) || defined(__gfx950__)
    unsafeAtomicAdd(p, v);
#else
    atomicAdd(p, v);
#endif
}

__device__ __forceinline__ float bf2f(unsigned int u) {
    union { float f; unsigned int i; } x; x.i = u << 16; return x.f;
}
__device__ __forceinline__ unsigned short f2bf(float f) {
    union { float f; unsigned int u; } x; x.f = f;
    unsigned int r = x.u + 0x7fff + ((x.u >> 16) & 1);
    return (unsigned short)(r >> 16);
}
__device__ __forceinline__ void accum8(float* qa, uint4 u) {
    qa[0] += bf2f(u.x & 0xffff); qa[1] += bf2f(u.x >> 16);
    qa[2] += bf2f(u.y & 0xffff); qa[3] += bf2f(u.y >> 16);
    qa[4] += bf2f(u.z & 0xffff); qa[5] += bf2f(u.z >> 16);
    qa[6] += bf2f(u.w & 0xffff); qa[7] += bf2f(u.w >> 16);
}
// edge-parallel LDS f32 accumulate of 8 bf16
__device__ __forceinline__ void atomAcc8(float* ar, uint4 u) {
    atomicAdd(&ar[0], bf2f(u.x & 0xffff)); atomicAdd(&ar[1], bf2f(u.x >> 16));
    atomicAdd(&ar[2], bf2f(u.y & 0xffff)); atomicAdd(&ar[3], bf2f(u.y >> 16));
    atomicAdd(&ar[4], bf2f(u.z & 0xffff)); atomicAdd(&ar[5], bf2f(u.z >> 16));
    atomicAdd(&ar[6], bf2f(u.w & 0xffff)); atomicAdd(&ar[7], bf2f(u.w >> 16));
}

// ---- fused: per-chunk coarse dst histogram (blocks 0..195) + convX/convW ----
__global__ __launch_bounds__(256) void k_h1cx(
    const int* __restrict__ dst,
    int* __restrict__ blockHist,
    const float* __restrict__ h, unsigned short* __restrict__ x1,
    const float* __restrict__ W1, const float* __restrict__ Ws1,
    const float* __restrict__ W2, const float* __restrict__ Ws2,
    unsigned short* __restrict__ Wb)
{
    __shared__ int hl[NCOARSE];
    int t = threadIdx.x;
    if (blockIdx.x < NCH) {
        int b = blockIdx.x;
        for (int i = t; i < NCOARSE; i += 256) hl[i] = 0;
        __syncthreads();
        int e0 = b * CHSZ;
        int eend = min(e0 + CHSZ, N_EDGES);
        for (int e = e0 + t; e < eend; e += 256)
            atomicAdd(&hl[dst[e] >> 6], 1);              // LDS atomic
        __syncthreads();
        for (int i = t; i < NCOARSE; i += 256) blockHist[b * NCOARSE + i] = hl[i];
    } else {
        int id = (blockIdx.x - NCH) * 256 + t;
        if (id < N_PAD * DIM) {
            int v = id >> 7;
            x1[id] = (v < N_NODES) ? f2bf(h[id]) : (unsigned short)0;
        } else {
            int tt = id - N_PAD * DIM;
            int l = tt / 278528, rem = tt % 278528;
            int r = rem >> 14, rr = rem & 16383;
            int n = rr >> 7, k = rr & 127;
            const float* W  = l ? W2 : W1;
            const float* Ws = l ? Ws2 : Ws1;
            float v = (r < 16) ? W[r * 16384 + k * 128 + n] : Ws[k * 128 + n];
            Wb[tt] = f2bf(v);
        }
    }
}

// ---- per-bin scan across chunks (parallel, 782 blocks) ----
__global__ __launch_bounds__(256) void k_csA(int* __restrict__ blockHist,
                                             int* __restrict__ cOffs)
{
    __shared__ int sc[2][256];
    int i = blockIdx.x, t = threadIdx.x;
    int v = (t < NCH) ? blockHist[t * NCOARSE + i] : 0;
    sc[0][t] = v; __syncthreads();
    int cur = 0;
    for (int o = 1; o < 256; o <<= 1) {
        sc[cur ^ 1][t] = sc[cur][t] + ((t >= o) ? sc[cur][t - o] : 0);
        __syncthreads();
        cur ^= 1;
    }
    if (t < NCH) blockHist[t * NCOARSE + i] = sc[cur][t] - v;   // exclusive, no base
    if (t == NCH - 1) cOffs[i] = sc[cur][t];                    // bin total
}

// ---- bin-base scan (1 block) ----
__global__ __launch_bounds__(1024) void k_csB(int* __restrict__ cOffs)
{
    __shared__ int c1[1024], c2[1024];
    int t = threadIdx.x;
    int v = (t < NCOARSE) ? cOffs[t] : 0;
    c1[t] = v; __syncthreads();
    int* cur = c1; int* nxt = c2;
    for (int o = 1; o < 1024; o <<= 1) {
        nxt[t] = cur[t] + ((t >= o) ? cur[t - o] : 0);
        __syncthreads();
        int* tmp = cur; cur = nxt; nxt = tmp;
    }
    if (t < NCOARSE) cOffs[t] = cur[t] - v;          // exclusive base
    if (t == NCOARSE) cOffs[NCOARSE] = cur[NCOARSE - 1];
}

// ---- scatter to coarse segments: record = src<<10 | rel<<6 | dstlow6 ----
__global__ __launch_bounds__(256) void k_scat1(
    const int* __restrict__ src, const int* __restrict__ dst, const int* __restrict__ rel,
    const int* __restrict__ blockHist, const int* __restrict__ cOffs,
    unsigned int* __restrict__ rtmp)
{
    __shared__ int baseL[NCOARSE];
    __shared__ int hl[NCOARSE];
    int b = blockIdx.x, t = threadIdx.x;
    for (int i = t; i < NCOARSE; i += 256) {
        baseL[i] = blockHist[b * NCOARSE + i] + cOffs[i];
        hl[i] = 0;
    }
    __syncthreads();
    int e0 = b * CHSZ;
    int eend = min(e0 + CHSZ, N_EDGES);
    for (int e = e0 + t; e < eend; e += 256) {
        int d = dst[e];
        int c = d >> 6;
        int rank = atomicAdd(&hl[c], 1);                 // LDS atomic
        rtmp[baseL[c] + rank] = ((unsigned int)src[e] << 10)
                              | ((unsigned int)rel[e] << 6)
                              | (unsigned int)(d & 63);
    }
}

// ---- per coarse bin: 1024-way (rel<<6|dstlow) counting sort ->
//      recs = src<<6|dstlow (rel-major contiguous) + CSR offsets ----
__global__ __launch_bounds__(256) void k_p2(
    const unsigned int* __restrict__ rtmp, const int* __restrict__ cOffs,
    unsigned int* __restrict__ recs, int* __restrict__ offsDR)
{
    __shared__ int cnt[1024];
    __shared__ int part[256], part2[256];
    int i = blockIdx.x, t = threadIdx.x;
    int segB = cOffs[i], segE = cOffs[i + 1];
    for (int k = t; k < 1024; k += 256) cnt[k] = 0;
    __syncthreads();
    for (int e = segB + t; e < segE; e += 256)
        atomicAdd(&cnt[rtmp[e] & 1023u], 1);
    __syncthreads();
    int b4 = t * 4;
    int s0 = cnt[b4], s1 = cnt[b4+1], s2 = cnt[b4+2], s3 = cnt[b4+3];
    int tsum = s0 + s1 + s2 + s3;
    part[t] = tsum;
    __syncthreads();
    int* cur = part; int* nxt = part2;
    for (int o = 1; o < 256; o <<= 1) {
        nxt[t] = cur[t] + ((t >= o) ? cur[t - o] : 0);
        __syncthreads();
        int* tmp = cur; cur = nxt; nxt = tmp;
    }
    int excl = cur[t] - tsum + segB;
    // offsDR from registers (no read race with scatter's atomics)
    offsDR[i * 1024 + b4]     = excl;
    offsDR[i * 1024 + b4 + 1] = excl + s0;
    offsDR[i * 1024 + b4 + 2] = excl + s0 + s1;
    offsDR[i * 1024 + b4 + 3] = excl + s0 + s1 + s2;
    if (i == NCOARSE - 1 && t == 0) offsDR[NCOARSE * 1024] = segE;
    cnt[b4]     = excl;
    cnt[b4 + 1] = excl + s0;
    cnt[b4 + 2] = excl + s0 + s1;
    cnt[b4 + 3] = excl + s0 + s1 + s2;
    __syncthreads();
    for (int e = segB + t; e < segE; e += 256) {
        unsigned int r = rtmp[e];
        int pos = atomicAdd(&cnt[r & 1023u], 1);
        recs[pos] = ((r >> 10) << 6) | (r & 63u);        // src<<6 | dstlow
    }
}

// ---- fused RGCN layer, edge-parallel build ----
// Per 64-dst bin: for each rel, edges are contiguous (rel-major sort).
// Build: 32 edges in flight, 8 thr/edge, coalesced 256B x-row reads,
// atomicAdd into f32 LDS acc (133-padded rows). Convert&zero fused; MFMA(r)
// shares a phase with edgepass(r+1) so edge latency hides under MFMA.
__global__ __launch_bounds__(256) void k_rgcn(
    const unsigned short* __restrict__ x, const unsigned short* __restrict__ Wb,
    const unsigned int* __restrict__ recs, const int* __restrict__ offsDR,
    const float* __restrict__ bias, unsigned short* __restrict__ out, int relu)
{
    __shared__ float accL[64][133];                      // 34048 B, bank-spread pad
    __shared__ __attribute__((aligned(16))) unsigned short S[64 * 136];  // 17408 B
    __shared__ int sOffs[17];
    int tid = threadIdx.x;
    int bin = blockIdx.x;
    int v0 = bin * 64;
    if (tid < 17) sOffs[tid] = offsDR[bin * 1024 + tid * 64];
    {
        float* af = &accL[0][0];
        for (int k = tid; k < 64 * 133; k += 256) af[k] = 0.f;
    }
    __syncthreads();

    int w = tid >> 6, l = tid & 63, nl = l & 15, q = l >> 4;
    int es = tid & 7, eg = tid >> 3;                     // 32 edges in flight

    f32x4 racc[4][2];
    #pragma unroll
    for (int m = 0; m < 4; ++m) {
        racc[m][0] = (f32x4){0.f, 0.f, 0.f, 0.f};
        racc[m][1] = (f32x4){0.f, 0.f, 0.f, 0.f};
    }

    auto edgepass = [&](int rr) {
        int o0 = sOffs[rr], o1 = sOffs[rr + 1];
        for (int e = o0 + eg; e < o1; e += 32) {
            unsigned int rec = recs[e];
            int dl = rec & 63;
            const uint4* xp = (const uint4*)(x + ((size_t)(rec >> 6)) * DIM + es * 16);
            uint4 u0 = xp[0], u1 = xp[1];
            float* ar = &accL[dl][es * 16];
            atomAcc8(ar, u0);
            atomAcc8(ar + 8, u1);
        }
    };

    edgepass(0);
    __syncthreads();

    for (int r = 0; r < 16; ++r) {
        // convert acc -> bf16 S, and zero acc for next rel
        {
            int crow = tid >> 2, cc = tid & 3;
            float* ap = &accL[crow][cc * 32];
            unsigned int* sp = (unsigned int*)&S[crow * 136 + cc * 32];
            #pragma unroll
            for (int j = 0; j < 16; ++j) {
                float f0 = ap[2*j], f1 = ap[2*j + 1];
                sp[j] = ((unsigned int)f2bf(f1) << 16) | f2bf(f0);
                ap[2*j] = 0.f; ap[2*j + 1] = 0.f;
            }
        }
        __syncthreads();
        // MFMA(r) then edgepass(r+1): edge loads hide under MFMA issue
        {
            const unsigned short* wr = Wb + r * 16384;
            bf16x8 b0[4], b1[4];
            #pragma unroll
            for (int kc = 0; kc < 4; ++kc) {
                b0[kc] = *(const bf16x8*)(wr + (w * 32 + nl) * 128 + kc * 32 + q * 8);
                b1[kc] = *(const bf16x8*)(wr + (w * 32 + 16 + nl) * 128 + kc * 32 + q * 8);
            }
            #pragma unroll
            for (int kc = 0; kc < 4; ++kc) {
                #pragma unroll
                for (int m = 0; m < 4; ++m) {
                    bf16x8 a = *(const bf16x8*)(&S[(m * 16 + nl) * 136 + kc * 32 + q * 8]);
                    racc[m][0] = __builtin_amdgcn_mfma_f32_16x16x32_bf16(a, b0[kc], racc[m][0], 0, 0, 0);
                    racc[m][1] = __builtin_amdgcn_mfma_f32_16x16x32_bf16(a, b1[kc], racc[m][1], 0, 0, 0);
                }
            }
        }
        if (r < 15) edgepass(r + 1);
        __syncthreads();
    }

    // self-loop: S = x[dst] rows directly (bf16 copy)
    #pragma unroll
    for (int hf = 0; hf < 2; ++hf) {
        int g = hf * 32 + eg;
        const uint4* xp = (const uint4*)(x + (size_t)(v0 + g) * DIM + es * 16);
        uint4 u0 = xp[0], u1 = xp[1];
        *(uint4*)(&S[g * 136 + es * 16])     = u0;
        *(uint4*)(&S[g * 136 + es * 16 + 8]) = u1;
    }
    __syncthreads();
    {
        const unsigned short* wr = Wb + 16 * 16384;
        bf16x8 b0[4], b1[4];
        #pragma unroll
        for (int kc = 0; kc < 4; ++kc) {
            b0[kc] = *(const bf16x8*)(wr + (w * 32 + nl) * 128 + kc * 32 + q * 8);
            b1[kc] = *(const bf16x8*)(wr + (w * 32 + 16 + nl) * 128 + kc * 32 + q * 8);
        }
        #pragma unroll
        for (int kc = 0; kc < 4; ++kc) {
            #pragma unroll
            for (int m = 0; m < 4; ++m) {
                bf16x8 a = *(const bf16x8*)(&S[(m * 16 + nl) * 136 + kc * 32 + q * 8]);
                racc[m][0] = __builtin_amdgcn_mfma_f32_16x16x32_bf16(a, b0[kc], racc[m][0], 0, 0, 0);
                racc[m][1] = __builtin_amdgcn_mfma_f32_16x16x32_bf16(a, b1[kc], racc[m][1], 0, 0, 0);
            }
        }
    }
    __syncthreads();

    // epilogue: bias + relu -> S staging -> coalesced store
    float bv0 = bias[w * 32 + nl], bv1 = bias[w * 32 + 16 + nl];
    #pragma unroll
    for (int m = 0; m < 4; ++m) {
        #pragma unroll
        for (int reg = 0; reg < 4; ++reg) {
            int row = m * 16 + q * 4 + reg;
            float f0 = racc[m][0][reg] + bv0;
            float f1 = racc[m][1][reg] + bv1;
            if (relu) { f0 = fmaxf(f0, 0.f); f1 = fmaxf(f1, 0.f); }
            S[row * 136 + (w * 32 + nl)]      = f2bf(f0);
            S[row * 136 + (w * 32 + 16 + nl)] = f2bf(f1);
        }
    }
    __syncthreads();
    {
        unsigned short* Ob = out + (size_t)v0 * DIM;
        #pragma unroll
        for (int it = 0; it < 4; ++it) {
            int c = tid + it * 256;
            int rw = c >> 4, k8 = c & 15;
            uint4 vv = *(const uint4*)(&S[rw * 136 + k8 * 8]);
            *(uint4*)(Ob + rw * DIM + k8 * 8) = vv;
        }
    }
}

__global__ void k_pool(const unsigned short* __restrict__ agg2, const int* __restrict__ gids,
                       float* __restrict__ hg_sum, int* __restrict__ cnt)
{
    int d  = threadIdx.x;
    int n0 = blockIdx.x * POOL_CH;
    int nend = min(n0 + POOL_CH, N_NODES);
    if (n0 >= N_NODES) return;
    int curg = gids[n0];
    float run = 0.f;
    for (int n = n0; n < nend; ++n) {
        int g = gids[n];
        if (g != curg) { atomAddF(&hg_sum[curg*DIM + d], run); run = 0.f; curg = g; }
        run += fmaxf(bf2f((unsigned int)agg2[n*DIM + d]), 0.f);
    }
    atomAddF(&hg_sum[curg*DIM + d], run);
    if (d == 0) {
        int cg = gids[n0]; int rl = 0;
        for (int n = n0; n < nend; ++n) {
            int g = gids[n];
            if (g != cg) { atomicAdd(&cnt[cg], rl); rl = 0; cg = g; }
            rl++;
        }
        atomicAdd(&cnt[cg], rl);
    }
}

__global__ __launch_bounds__(256) void k_head(
    const float* __restrict__ hg_sum, const int* __restrict__ cnt,
    const float* __restrict__ Wfc, const float* __restrict__ bfc,
    const float* __restrict__ Wc, const float* __restrict__ bc,
    float* __restrict__ out)
{
    int g = blockIdx.x, t = threadIdx.x;
    __shared__ float hgl[DIM];
    __shared__ float fcl[FC_DIM];
    __shared__ float lg[N_CLASSES];
    if (t < DIM) {
        float c = (float)max(cnt[g], 1);
        hgl[t] = hg_sum[g*DIM + t] / c;
    }
    __syncthreads();
    {
        float sv = bfc[t];
        #pragma unroll 4
        for (int k = 0; k < DIM; ++k) sv += hgl[k] * Wfc[k*FC_DIM + t];
        fcl[t] = fmaxf(sv, 0.f);
    }
    __syncthreads();
    if (t < N_CLASSES) {
        float lgt = bc[t];
        #pragma unroll 4
        for (int k = 0; k < FC_DIM; ++k) lgt += fcl[k] * Wc[k*N_CLASSES + t];
        lg[t] = lgt;
    }
    __syncthreads();
    if (t < N_CLASSES) {
        float m = lg[0];
        #pragma unroll
        for (int c = 1; c < N_CLASSES; ++c) m = fmaxf(m, lg[c]);
        float sden = 0.f;
        #pragma unroll
        for (int c = 0; c < N_CLASSES; ++c) sden += expf(lg[c] - m);
        out[g*N_CLASSES + t] = expf(lg[t] - m) / sden;
    }
}

extern "C" void kernel_launch(void* const* d_in, const int* in_sizes, int n_in,
                              void* d_out, int out_size, void* d_ws, size_t ws_size,
                              hipStream_t stream)
{
    const float* h   = (const float*)d_in[0];
    const int*   src = (const int*)d_in[1];
    const int*   dst = (const int*)d_in[2];
    const int*   rel = (const int*)d_in[3];
    const int*   gid = (const int*)d_in[4];
    const float* W1  = (const float*)d_in[5];
    const float* Ws1 = (const float*)d_in[6];
    const float* b1  = (const float*)d_in[7];
    const float* W2  = (const float*)d_in[8];
    const float* Ws2 = (const float*)d_in[9];
    const float* b2  = (const float*)d_in[10];
    const float* Wfc = (const float*)d_in[11];
    const float* bfc = (const float*)d_in[12];
    const float* Wc  = (const float*)d_in[13];
    const float* bc  = (const float*)d_in[14];
    float* out = (float*)d_out;

    char* ws = (char*)d_ws;
    float* hgsum = (float*)(ws + WS_HG);
    int*   cnt   = (int*)(ws + WS_CNT);
    int*   blkH  = (int*)(ws + WS_BLKH);
    int*   cOffs = (int*)(ws + WS_COFS);
    unsigned int* rtmp = (unsigned int*)(ws + WS_RTMP);
    unsigned int* recs = (unsigned int*)(ws + WS_RECS);
    int*   offsDR = (int*)(ws + WS_OFFSDR);
    unsigned short* x1  = (unsigned short*)(ws + WS_X1);
    unsigned short* x2  = (unsigned short*)(ws + WS_X2);
    unsigned short* agg = (unsigned short*)(ws + WS_AGG);
    unsigned short* Wb  = (unsigned short*)(ws + WS_WB);

    hipMemsetAsync(ws + WS_HG, 0, MEMSET_SZ, stream);   // hg + cnt

    k_h1cx<<<NCH + NBLK_CX, 256, 0, stream>>>(dst, blkH, h, x1, W1, Ws1, W2, Ws2, Wb);
    k_csA<<<NCOARSE, 256, 0, stream>>>(blkH, cOffs);
    k_csB<<<1, 1024, 0, stream>>>(cOffs);
    k_scat1<<<NCH, 256, 0, stream>>>(src, dst, rel, blkH, cOffs, rtmp);
    k_p2<<<NCOARSE, 256, 0, stream>>>(rtmp, cOffs, recs, offsDR);

    k_rgcn<<<NCOARSE, 256, 0, stream>>>(x1, Wb, recs, offsDR, b1, x2, 1);
    k_rgcn<<<NCOARSE, 256, 0, stream>>>(x2, Wb + 17 * 16384, recs, offsDR, b2, agg, 0);

    k_pool<<<(N_PAD + POOL_CH - 1) / POOL_CH, 128, 0, stream>>>(agg, gid, hgsum, cnt);
    k_head<<<N_GRAPHS, 256, 0, stream>>>(hgsum, cnt, Wfc, bfc, Wc, bc, out);
}

// Round 8
// 408.925 us; speedup vs baseline: 4.2509x; 4.2509x over previous
//
#include <hip/hip_runtime.h>
#include <hip/hip_bf16.h>

#define N_NODES   50000
#define N_PAD     50048                 // ceil64
#define N_EDGES   800000
#define N_REL     16
#define N_GRAPHS  64
#define DIM       128
#define FC_DIM    256
#define N_CLASSES 16

#define SB        50176                 // src bins per rel (49*1024)
#define NBINS_P   (16 * SB)             // 802816
#define NBLK_PP   784
#define NCOARSE   782                   // dst>>6 bins
#define NCH       98                    // edge chunks
#define CHSZ      8192
#define POOL_CH   64
// virtual blocks for phase A: 98 chunks * 17 rels * 8 = covers i<=783 per rel
#define NBVIRT    13328
#define GRID_A    1024                  // 4 blocks/CU resident; grid-stride + pipeline

#define NBLK_CX   27200                 // XW_TOTAL/256
#define XW_TOTAL  (N_PAD * DIM + 2 * 17 * 16384)

// ---- ws layout (bytes, 256-aligned) ----
#define WS_MARK   0                     // 802816  } contiguous
#define WS_HG     802816                // 32768   } memset
#define WS_CNT    835584                // 256     } region
#define WS_SRCOF  835840                // 3203072 } (pads must be 0)
#define MEMSET_SZ 4038912
#define WS_BLKH   4038912               // 98*782*4 = 306544 -> 306688
#define WS_COFS   4345600               // 3328
#define WS_PARTP  4348928               // 3328
#define WS_BLKB   4352256               // 3328
#define WS_RELB   4355584               // 256
#define WS_CIDMAP 4355840               // 3211264
#define WS_RTMP   7567104               // 3200000
#define WS_RECS   10767104              // 3200000
#define WS_OFFSD  13967104              // 200448
#define WS_X1     14167552              // 12812288
#define WS_X2     26979840              // 12812288
#define WS_AGG    39792128              // 12812288 (bf16)
#define WS_WB     52604416              // 1114112
#define WS_T      53718528              // + rows*256B (actual ~142MB)

typedef __attribute__((ext_vector_type(8))) short bf16x8;
typedef __attribute__((ext_vector_type(4))) float f32x4;

__device__ __forceinline__ void atomAddF(float* p, float v) {
#if defined(__gfx90a__) || defined(__gfx942__) || defined(__gfx950__)
    unsafeAtomicAdd(p, v);
#else
    atomicAdd(p, v);
#endif
}

__device__ __forceinline__ float bf2f(unsigned int u) {
    union { float f; unsigned int i; } x; x.i = u << 16; return x.f;
}
__device__ __forceinline__ unsigned short f2bf(float f) {
    union { float f; unsigned int u; } x; x.f = f;
    unsigned int r = x.u + 0x7fff + ((x.u >> 16) & 1);
    return (unsigned short)(r >> 16);
}
__device__ __forceinline__ void accum8(float* qa, uint4 u) {
    qa[0] += bf2f(u.x & 0xffff); qa[1] += bf2f(u.x >> 16);
    qa[2] += bf2f(u.y & 0xffff); qa[3] += bf2f(u.y >> 16);
    qa[4] += bf2f(u.z & 0xffff); qa[5] += bf2f(u.z >> 16);
    qa[6] += bf2f(u.w & 0xffff); qa[7] += bf2f(u.w >> 16);
}
__device__ __forceinline__ void pack16(const float* qa, unsigned short* dst) {
    #pragma unroll
    for (int j = 0; j < 2; ++j) {
        uint4 w;
        w.x = ((unsigned int)f2bf(qa[j*8+1]) << 16) | f2bf(qa[j*8+0]);
        w.y = ((unsigned int)f2bf(qa[j*8+3]) << 16) | f2bf(qa[j*8+2]);
        w.z = ((unsigned int)f2bf(qa[j*8+5]) << 16) | f2bf(qa[j*8+4]);
        w.w = ((unsigned int)f2bf(qa[j*8+7]) << 16) | f2bf(qa[j*8+6]);
        ((uint4*)dst)[j] = w;
    }
}

// ---- fused: h1 (blocks 0..97, runs first) + convXW (blocks 98..) ----
// h1 and convXW are independent; block-range fusion overlaps them in one
// dispatch (h1 first so its 98 blocks start immediately).
__global__ __launch_bounds__(256) void k_h1cx(
    const int* __restrict__ src, const int* __restrict__ dst, const int* __restrict__ rel,
    unsigned char* __restrict__ mark, int* __restrict__ blockHist,
    const float* __restrict__ h, unsigned short* __restrict__ x1,
    const float* __restrict__ W1, const float* __restrict__ Ws1,
    const float* __restrict__ W2, const float* __restrict__ Ws2,
    unsigned short* __restrict__ Wb)
{
    __shared__ int hl[NCOARSE];
    int t = threadIdx.x;
    if (blockIdx.x < NCH) {
        int b = blockIdx.x;
        for (int i = t; i < NCOARSE; i += 256) hl[i] = 0;
        __syncthreads();
        int e0 = b * CHSZ;
        int eend = min(e0 + CHSZ, N_EDGES);
        for (int e = e0 + t; e < eend; e += 256) {
            int d = dst[e];
            mark[rel[e] * SB + src[e]] = 1;
            atomicAdd(&hl[d >> 6], 1);                   // LDS atomic
        }
        __syncthreads();
        for (int i = t; i < NCOARSE; i += 256) blockHist[b * NCOARSE + i] = hl[i];
    } else {
        int id = (blockIdx.x - NCH) * 256 + t;
        if (id < N_PAD * DIM) {
            int v = id >> 7;
            x1[id] = (v < N_NODES) ? f2bf(h[id]) : (unsigned short)0;
        } else {
            int tt = id - N_PAD * DIM;
            int l = tt / 278528, rem = tt % 278528;
            int r = rem >> 14, rr = rem & 16383;
            int n = rr >> 7, k = rr & 127;
            const float* W  = l ? W2 : W1;
            const float* Ws = l ? Ws2 : Ws1;
            float v = (r < 16) ? W[r * 16384 + k * 128 + n] : Ws[k * 128 + n];
            Wb[tt] = f2bf(v);
        }
    }
}

// ---- fused: scanPA (blocks 0..783) + parallel per-bin chunk scan cscanA
// (blocks 784..1565). Both depend only on h1's outputs. cscanA replaces the
// old single-block serial 98-loop cscan: block i scans its bin's 98 chunk
// counts in LDS (7-step Hillis-Steele), writes back exclusive-without-base,
// and emits the bin total into cOffs[i] (scanned by cscanB next).
__global__ __launch_bounds__(256) void k_sA(
    const unsigned int* __restrict__ markU, int* __restrict__ partP,
    int* __restrict__ blockHist, int* __restrict__ cOffs)
{
    int t = threadIdx.x;
    if (blockIdx.x < NBLK_PP) {
        __shared__ int red[256];
        int b = blockIdx.x;
        unsigned int u = markU[b * 256 + t];
        red[t] = (int)((u & 1) + ((u >> 8) & 1) + ((u >> 16) & 1) + ((u >> 24) & 1));
        __syncthreads();
        for (int o = 128; o > 0; o >>= 1) {
            if (t < o) red[t] += red[t + o];
            __syncthreads();
        }
        if (t == 0) partP[b] = red[0];
    } else {
        __shared__ int sc[2][128];
        int i = blockIdx.x - NBLK_PP;                    // 0..781
        int v = 0;
        if (t < NCH) v = blockHist[t * NCOARSE + i];
        if (t < 128) sc[0][t] = v;
        __syncthreads();
        int cur = 0, nxt = 1;
        #pragma unroll
        for (int o = 1; o < 128; o <<= 1) {
            if (t < 128) sc[nxt][t] = sc[cur][t] + ((t >= o) ? sc[cur][t - o] : 0);
            __syncthreads();
            int tmp = cur; cur = nxt; nxt = tmp;
        }
        if (t < NCH) blockHist[t * NCOARSE + i] = sc[cur][t] - v;   // exclusive, no base
        if (t == NCH - 1) cOffs[i] = sc[cur][t];                    // bin total
    }
}

// ---- fused: scanPB (block 0) + cscanB (block 1). Independent of each other;
// both tiny single-block scans. cscanB turns cOffs bin totals into exclusive
// global bases in place (loads to LDS first).
__global__ __launch_bounds__(1024) void k_sB(
    const int* __restrict__ partP, int* __restrict__ blkB, int* __restrict__ relB,
    int* __restrict__ cOffs)
{
    int t = threadIdx.x;
    if (blockIdx.x == 0) {
        __shared__ int s1[784], s2[784];
        __shared__ int tot[16], rbase[17];
        int rel = t / 49, pos = t - rel * 49;
        int v = (t < 784) ? partP[t] : 0;
        if (t < 784) s1[t] = v;
        __syncthreads();
        int* cur = s1; int* nxt = s2;
        for (int o = 1; o < 64; o <<= 1) {
            if (t < 784) nxt[t] = cur[t] + ((pos >= o) ? cur[t - o] : 0);
            __syncthreads();
            int* tmp = cur; cur = nxt; nxt = tmp;
        }
        if (t < 784 && pos == 48) tot[rel] = cur[t];
        __syncthreads();
        if (t == 0) {
            int base = 0;
            for (int r = 0; r < 16; ++r) { rbase[r] = base; base += (tot[r] + 63) & ~63; }
            rbase[16] = base;
        }
        __syncthreads();
        if (t < 784) blkB[t] = rbase[rel] + cur[t] - v;
        if (t < 17)  relB[t] = rbase[t];
    } else {
        __shared__ int c1[1024], c2[1024];
        int v = (t < NCOARSE) ? cOffs[t] : 0;
        c1[t] = v; __syncthreads();
        int* cur = c1; int* nxt = c2;
        for (int o = 1; o < 1024; o <<= 1) {
            nxt[t] = cur[t] + ((t >= o) ? cur[t - o] : 0);
            __syncthreads();
            int* tmp = cur; cur = nxt; nxt = tmp;
        }
        if (t < NCOARSE) cOffs[t] = cur[t] - v;          // exclusive base
        if (t == NCOARSE) cOffs[NCOARSE] = cur[NCOARSE - 1];
    }
}

__global__ void k_scanPC(const unsigned int* __restrict__ markU, const int* __restrict__ blkB,
                         int* __restrict__ cidMap, int* __restrict__ srcOf) {
    __shared__ int s1[256], s2[256];
    int b = blockIdx.x, t = threadIdx.x;
    unsigned int u = markU[b * 256 + t];
    int f0 = (int)(u & 1), f1 = (int)((u >> 8) & 1);
    int f2 = (int)((u >> 16) & 1), f3 = (int)((u >> 24) & 1);
    int sum = f0 + f1 + f2 + f3;
    s1[t] = sum; __syncthreads();
    int* cur = s1; int* nxt = s2;
    for (int o = 1; o < 256; o <<= 1) {
        nxt[t] = cur[t] + ((t >= o) ? cur[t - o] : 0);
        __syncthreads();
        int* tmp = cur; cur = nxt; nxt = tmp;
    }
    int cid = blkB[b] + cur[t] - sum;
    int rel = b / 49;
    int key0 = b * 1024 + t * 4;
    int srcBase = key0 - rel * SB;
    if (f0) { cidMap[key0]     = cid; srcOf[cid] = srcBase;     cid++; }
    if (f1) { cidMap[key0 + 1] = cid; srcOf[cid] = srcBase + 1; cid++; }
    if (f2) { cidMap[key0 + 2] = cid; srcOf[cid] = srcBase + 2; cid++; }
    if (f3) { cidMap[key0 + 3] = cid; srcOf[cid] = srcBase + 3; cid++; }
}

// ---- sort pass 1b: scatter to coarse segments. Global bin base (cOffs)
// added here (was baked into blockHist by the old serial cscan). ----
__global__ __launch_bounds__(256) void k_scat1(
    const int* __restrict__ src, const int* __restrict__ dst, const int* __restrict__ rel,
    const int* __restrict__ cidMap, const int* __restrict__ blockHist,
    const int* __restrict__ cOffs, unsigned int* __restrict__ rtmp)
{
    __shared__ int baseL[NCOARSE];
    __shared__ int hl[NCOARSE];
    int b = blockIdx.x, t = threadIdx.x;
    for (int i = t; i < NCOARSE; i += 256) {
        baseL[i] = blockHist[b * NCOARSE + i] + cOffs[i];
        hl[i] = 0;
    }
    __syncthreads();
    int e0 = b * CHSZ;
    int eend = min(e0 + CHSZ, N_EDGES);
    for (int e = e0 + t; e < eend; e += 256) {
        int d = dst[e];
        int cid = cidMap[rel[e] * SB + src[e]];
        int c = d >> 6;
        int rank = atomicAdd(&hl[c], 1);                 // LDS atomic
        rtmp[baseL[c] + rank] = ((unsigned int)cid << 6) | (unsigned int)(d & 63);
    }
}

// ---- sort pass 2: per coarse bin, final 64-way local sort + offsD ----
__global__ __launch_bounds__(256) void k_p2(
    const unsigned int* __restrict__ rtmp, const int* __restrict__ coarseOffs,
    unsigned int* __restrict__ recs, int* __restrict__ offsD)
{
    __shared__ int cntL[64], exclL[65], cur2[64];
    int i = blockIdx.x, t = threadIdx.x;
    int segB = coarseOffs[i], segE = coarseOffs[i + 1];
    if (t < 64) { cntL[t] = 0; cur2[t] = 0; }
    __syncthreads();
    for (int e = segB + t; e < segE; e += 256)
        atomicAdd(&cntL[rtmp[e] & 63u], 1);
    __syncthreads();
    if (t == 0) {
        int run = segB;
        #pragma unroll
        for (int d = 0; d < 64; ++d) { exclL[d] = run; run += cntL[d]; }
        exclL[64] = run;
    }
    __syncthreads();
    if (t < 64) offsD[i * 64 + t] = exclL[t];
    if (t == 64) offsD[i * 64 + 64] = exclL[64];
    for (int e = segB + t; e < segE; e += 256) {
        unsigned int r = rtmp[e];
        int d = (int)(r & 63u);
        int rank = atomicAdd(&cur2[d], 1);               // LDS atomic
        recs[exclL[d] + rank] = r >> 6;
    }
}

// ---- Phase A: gather-GEMM over compact rows (r3 structure, unchanged) ----
__global__ __launch_bounds__(256) void k_phaseA(
    const unsigned short* __restrict__ x, const unsigned short* __restrict__ Wb,
    const int* __restrict__ srcOf, const int* __restrict__ relB,
    unsigned short* __restrict__ T)
{
    __shared__ __attribute__((aligned(16))) unsigned short Xs[64 * 136];
    __shared__ __attribute__((aligned(16))) unsigned short Cs[64 * 136];
    __shared__ int sRB[17];

    int tid = threadIdx.x;
    if (tid < 17) sRB[tid] = relB[tid];
    __syncthreads();
    int rtot = sRB[16];

    int row = tid >> 2, c0 = tid & 3;

    auto tileInfo = [&](int vb, int& trow0, int& tr) -> bool {
        int chunk = vb / 136;
        int lane = vb - chunk * 136;
        int r = lane >> 3;
        int i = chunk * 8 + (lane & 7);
        int base, cnt;
        if (r == 16) { base = rtot; cnt = N_PAD / 64; }
        else         { base = sRB[r]; cnt = (sRB[r + 1] - base) >> 6; }
        if (i >= cnt) return false;
        trow0 = base + i * 64; tr = r;
        return true;
    };

    int vb = blockIdx.x;
    int cur_row0, cur_r;
    while (vb < NBVIRT && !tileInfo(vb, cur_row0, cur_r)) vb += gridDim.x;
    if (vb >= NBVIRT) return;

    uint4 g0, g1, g2, g3;
    {
        int sr = (cur_r == 16) ? (cur_row0 - rtot + row) : srcOf[cur_row0 + row];
        const uint4* xp = (const uint4*)(x + (size_t)sr * DIM);
        g0 = xp[c0]; g1 = xp[c0 + 4]; g2 = xp[c0 + 8]; g3 = xp[c0 + 12];
    }

    int w = tid >> 6, l = tid & 63;
    int nl = l & 15, q = l >> 4;

    while (true) {
        {
            uint4* lp = (uint4*)(&Xs[row * 136]);
            lp[c0] = g0; lp[c0 + 4] = g1; lp[c0 + 8] = g2; lp[c0 + 12] = g3;
        }
        bf16x8 Bf[2][4];
        {
            const unsigned short* wr = Wb + cur_r * 16384;
            #pragma unroll
            for (int nt = 0; nt < 2; ++nt) {
                int n = w * 32 + nt * 16 + nl;
                #pragma unroll
                for (int kc = 0; kc < 4; ++kc)
                    Bf[nt][kc] = *(const bf16x8*)(wr + n * 128 + kc * 32 + q * 8);
            }
        }
        int nvb = vb + gridDim.x;
        int nxt_row0 = 0, nxt_r = 0;
        while (nvb < NBVIRT && !tileInfo(nvb, nxt_row0, nxt_r)) nvb += gridDim.x;
        bool nhave = (nvb < NBVIRT);
        if (nhave) {
            int sr = (nxt_r == 16) ? (nxt_row0 - rtot + row) : srcOf[nxt_row0 + row];
            const uint4* xp = (const uint4*)(x + (size_t)sr * DIM);
            g0 = xp[c0]; g1 = xp[c0 + 4]; g2 = xp[c0 + 8]; g3 = xp[c0 + 12];
        }
        __syncthreads();
        #pragma unroll
        for (int m = 0; m < 4; ++m) {
            f32x4 a0 = {0.f, 0.f, 0.f, 0.f}, a1 = {0.f, 0.f, 0.f, 0.f};
            #pragma unroll
            for (int kc = 0; kc < 4; ++kc) {
                bf16x8 a = *(const bf16x8*)(&Xs[(m * 16 + nl) * 136 + kc * 32 + q * 8]);
                a0 = __builtin_amdgcn_mfma_f32_16x16x32_bf16(a, Bf[0][kc], a0, 0, 0, 0);
                a1 = __builtin_amdgcn_mfma_f32_16x16x32_bf16(a, Bf[1][kc], a1, 0, 0, 0);
            }
            int colb = w * 32 + nl;
            #pragma unroll
            for (int reg = 0; reg < 4; ++reg) {
                int row2 = m * 16 + q * 4 + reg;
                int sw = ((row2 >> 3) & 1) << 4;
                Cs[row2 * 136 + (colb ^ sw)]        = f2bf(a0[reg]);
                Cs[row2 * 136 + ((colb + 16) ^ sw)] = f2bf(a1[reg]);
            }
        }
        __syncthreads();
        {
            unsigned short* Tb = T + (size_t)cur_row0 * DIM;
            #pragma unroll
            for (int it = 0; it < 4; ++it) {
                int c = tid + it * 256;
                int rw = c >> 4, k8 = c & 15;
                int sw = ((rw >> 3) & 1) << 4;
                uint4 vv = *(const uint4*)(&Cs[rw * 136 + ((k8 * 8) ^ sw)]);
                *(uint4*)(Tb + rw * DIM + k8 * 8) = vv;
            }
        }
        if (!nhave) break;
        vb = nvb; cur_row0 = nxt_row0; cur_r = nxt_r;
    }
}

// ---- Phase B: unchanged ----
__global__ __launch_bounds__(256) void k_phaseB(
    const unsigned short* __restrict__ T, const unsigned int* __restrict__ recs,
    const int* __restrict__ offsD, const int* __restrict__ relB,
    const float* __restrict__ bias,
    unsigned short* __restrict__ aggOut, int relu)
{
    __shared__ int sOffs[33];
    __shared__ float sBias[128];
    __shared__ int sSelf;
    int tid = threadIdx.x;
    int v0 = blockIdx.x * 32;
    if (tid < 33) sOffs[tid] = offsD[v0 + tid];
    if (tid == 40) sSelf = relB[16];
    if (tid >= 64 && tid < 96) ((float4*)sBias)[tid - 64] = ((const float4*)bias)[tid - 64];
    __syncthreads();

    int g = tid >> 3, s = tid & 7;
    int dst = v0 + g;
    float qa[16];
    #pragma unroll
    for (int i = 0; i < 16; ++i) qa[i] = sBias[s * 16 + i];

    int beg = sOffs[g], end = sOffs[g + 1];
    int e = beg;
    for (; e + 3 < end; e += 4) {
        unsigned int c0 = recs[e], c1 = recs[e+1], c2 = recs[e+2], c3 = recs[e+3];
        const uint4* t0 = (const uint4*)(T + (size_t)c0 * DIM + s * 16);
        const uint4* t1 = (const uint4*)(T + (size_t)c1 * DIM + s * 16);
        const uint4* t2 = (const uint4*)(T + (size_t)c2 * DIM + s * 16);
        const uint4* t3 = (const uint4*)(T + (size_t)c3 * DIM + s * 16);
        uint4 a0 = t0[0], a1 = t0[1], b0 = t1[0], b1 = t1[1];
        uint4 cc0 = t2[0], cc1 = t2[1], d0 = t3[0], d1 = t3[1];
        accum8(qa, a0); accum8(qa + 8, a1);
        accum8(qa, b0); accum8(qa + 8, b1);
        accum8(qa, cc0); accum8(qa + 8, cc1);
        accum8(qa, d0); accum8(qa + 8, d1);
    }
    for (; e < end; ++e) {
        unsigned int c = recs[e];
        const uint4* tp = (const uint4*)(T + (size_t)c * DIM + s * 16);
        uint4 u0 = tp[0], u1 = tp[1];
        accum8(qa, u0); accum8(qa + 8, u1);
    }
    {
        const uint4* tp = (const uint4*)(T + (size_t)(sSelf + dst) * DIM + s * 16);
        uint4 u0 = tp[0], u1 = tp[1];
        accum8(qa, u0); accum8(qa + 8, u1);
    }

    if (relu) {
        #pragma unroll
        for (int i = 0; i < 16; ++i) qa[i] = fmaxf(qa[i], 0.f);
    }
    pack16(qa, aggOut + (size_t)dst * DIM + s * 16);
}

__global__ void k_pool(const unsigned short* __restrict__ agg2, const int* __restrict__ gids,
                       float* __restrict__ hg_sum, int* __restrict__ cnt)
{
    int d  = threadIdx.x;
    int n0 = blockIdx.x * POOL_CH;
    int nend = min(n0 + POOL_CH, N_NODES);
    if (n0 >= N_NODES) return;
    int curg = gids[n0];
    float run = 0.f;
    for (int n = n0; n < nend; ++n) {
        int g = gids[n];
        if (g != curg) { atomAddF(&hg_sum[curg*DIM + d], run); run = 0.f; curg = g; }
        run += fmaxf(bf2f((unsigned int)agg2[n*DIM + d]), 0.f);
    }
    atomAddF(&hg_sum[curg*DIM + d], run);
    if (d == 0) {
        int cg = gids[n0]; int rl = 0;
        for (int n = n0; n < nend; ++n) {
            int g = gids[n];
            if (g != cg) { atomicAdd(&cnt[cg], rl); rl = 0; cg = g; }
            rl++;
        }
        atomicAdd(&cnt[cg], rl);
    }
}

__global__ __launch_bounds__(256) void k_head(
    const float* __restrict__ hg_sum, const int* __restrict__ cnt,
    const float* __restrict__ Wfc, const float* __restrict__ bfc,
    const float* __restrict__ Wc, const float* __restrict__ bc,
    float* __restrict__ out)
{
    int g = blockIdx.x, t = threadIdx.x;
    __shared__ float hgl[DIM];
    __shared__ float fcl[FC_DIM];
    __shared__ float lg[N_CLASSES];
    if (t < DIM) {
        float c = (float)max(cnt[g], 1);
        hgl[t] = hg_sum[g*DIM + t] / c;
    }
    __syncthreads();
    {
        float sv = bfc[t];
        #pragma unroll 4
        for (int k = 0; k < DIM; ++k) sv += hgl[k] * Wfc[k*FC_DIM + t];
        fcl[t] = fmaxf(sv, 0.f);
    }
    __syncthreads();
    if (t < N_CLASSES) {
        float lgt = bc[t];
        #pragma unroll 4
        for (int k = 0; k < FC_DIM; ++k) lgt += fcl[k] * Wc[k*N_CLASSES + t];
        lg[t] = lgt;
    }
    __syncthreads();
    if (t < N_CLASSES) {
        float m = lg[0];
        #pragma unroll
        for (int c = 1; c < N_CLASSES; ++c) m = fmaxf(m, lg[c]);
        float sden = 0.f;
        #pragma unroll
        for (int c = 0; c < N_CLASSES; ++c) sden += expf(lg[c] - m);
        out[g*N_CLASSES + t] = expf(lg[t] - m) / sden;
    }
}

extern "C" void kernel_launch(void* const* d_in, const int* in_sizes, int n_in,
                              void* d_out, int out_size, void* d_ws, size_t ws_size,
                              hipStream_t stream)
{
    const float* h   = (const float*)d_in[0];
    const int*   src = (const int*)d_in[1];
    const int*   dst = (const int*)d_in[2];
    const int*   rel = (const int*)d_in[3];
    const int*   gid = (const int*)d_in[4];
    const float* W1  = (const float*)d_in[5];
    const float* Ws1 = (const float*)d_in[6];
    const float* b1  = (const float*)d_in[7];
    const float* W2  = (const float*)d_in[8];
    const float* Ws2 = (const float*)d_in[9];
    const float* b2  = (const float*)d_in[10];
    const float* Wfc = (const float*)d_in[11];
    const float* bfc = (const float*)d_in[12];
    const float* Wc  = (const float*)d_in[13];
    const float* bc  = (const float*)d_in[14];
    float* out = (float*)d_out;

    char* ws = (char*)d_ws;
    unsigned char* mark = (unsigned char*)(ws + WS_MARK);
    float* hgsum = (float*)(ws + WS_HG);
    int*   cnt   = (int*)(ws + WS_CNT);
    int*   srcOf = (int*)(ws + WS_SRCOF);
    int*   blkH  = (int*)(ws + WS_BLKH);
    int*   cOffs = (int*)(ws + WS_COFS);
    int*   partP = (int*)(ws + WS_PARTP);
    int*   blkB  = (int*)(ws + WS_BLKB);
    int*   relB  = (int*)(ws + WS_RELB);
    int*   cidMap= (int*)(ws + WS_CIDMAP);
    unsigned int* rtmp = (unsigned int*)(ws + WS_RTMP);
    unsigned int* recs = (unsigned int*)(ws + WS_RECS);
    int*   offsD = (int*)(ws + WS_OFFSD);
    unsigned short* x1  = (unsigned short*)(ws + WS_X1);
    unsigned short* x2  = (unsigned short*)(ws + WS_X2);
    unsigned short* agg = (unsigned short*)(ws + WS_AGG);
    unsigned short* Wb  = (unsigned short*)(ws + WS_WB);
    unsigned short* T   = (unsigned short*)(ws + WS_T);

    hipMemsetAsync(mark, 0, MEMSET_SZ, stream);    // mark+hg+cnt+srcOf

    k_h1cx<<<NCH + NBLK_CX, 256, 0, stream>>>(src, dst, rel, mark, blkH,
                                              h, x1, W1, Ws1, W2, Ws2, Wb);
    k_sA<<<NBLK_PP + NCOARSE, 256, 0, stream>>>((const unsigned int*)mark, partP,
                                                blkH, cOffs);
    k_sB<<<2, 1024, 0, stream>>>(partP, blkB, relB, cOffs);
    k_scanPC<<<NBLK_PP, 256, 0, stream>>>((const unsigned int*)mark, blkB, cidMap, srcOf);

    k_scat1<<<NCH, 256, 0, stream>>>(src, dst, rel, cidMap, blkH, cOffs, rtmp);
    k_p2<<<NCOARSE, 256, 0, stream>>>(rtmp, cOffs, recs, offsD);

    k_phaseA<<<GRID_A, 256, 0, stream>>>(x1, Wb, srcOf, relB, T);
    k_phaseB<<<N_PAD / 32, 256, 0, stream>>>(T, recs, offsD, relB, b1, x2, 1);
    k_phaseA<<<GRID_A, 256, 0, stream>>>(x2, Wb + 17 * 16384, srcOf, relB, T);
    k_phaseB<<<N_PAD / 32, 256, 0, stream>>>(T, recs, offsD, relB, b2, agg, 0);

    k_pool<<<(N_PAD + POOL_CH - 1) / POOL_CH, 128, 0, stream>>>(agg, gid, hgsum, cnt);
    k_head<<<N_GRAPHS, 256, 0, stream>>>(hgsum, cnt, Wfc, bfc, Wc, bc, out);
}

// Round 9
// 377.039 us; speedup vs baseline: 4.6103x; 1.0846x over previous
//
#include <hip/hip_runtime.h>
#include <hip/hip_bf16.h>

#define N_NODES   50000
#define N_PAD     50048                 // ceil64
#define N_EDGES   800000
#define N_REL     16
#define N_GRAPHS  64
#define DIM       128
#define FC_DIM    256
#define N_CLASSES 16

#define SB        50176                 // src bins per rel (49*1024)
#define NBINS_P   (16 * SB)             // 802816
#define NBLK_PP   784
#define NCOARSE   782                   // dst>>6 bins
#define NCH       392                   // edge chunks (r9: 98->392, scat1 parallelism)
#define CHSZ      2048
// virtual blocks for phase A: fixed internal sweep chunking (independent of NCH)
#define NBVIRT    13328
#define GRID_A    1024                  // 4 blocks/CU resident; grid-stride + pipeline

#define NBLK_CX   27200                 // XW_TOTAL/256
#define XW_TOTAL  (N_PAD * DIM + 2 * 17 * 16384)

// ---- ws layout (bytes, 256-aligned) ----
#define WS_MARK   0                     // 802816  } contiguous
#define WS_HG     802816                // 32768   } memset
#define WS_CNT    835584                // 256     } region (hole, unused)
#define WS_SRCOF  835840                // 3203072 } (pads must be 0)
#define MEMSET_SZ 4038912
#define WS_BLKH   4038912               // 392*782*4 = 1226176 -> 1226240
#define WS_COFS   5265152               // 3328
#define WS_PARTP  5268480               // 3328
#define WS_BLKB   5271808               // 3328
#define WS_RELB   5275136               // 256
#define WS_CIDMAP 5275392               // 3211264
#define WS_RTMP   8486656               // 3200000
#define WS_RECS   11686656              // 3200000
#define WS_OFFSD  14886656              // 200448
#define WS_X1     15087104              // 12812288
#define WS_X2     27899392              // 12812288
#define WS_WB     40711680              // 1114112
#define WS_T      41825792              // + rows*256B (actual ~143MB)

typedef __attribute__((ext_vector_type(8))) short bf16x8;
typedef __attribute__((ext_vector_type(4))) float f32x4;

__device__ __forceinline__ void atomAddF(float* p, float v) {
#if defined(__gfx90a__) || defined(__gfx942__) || defined(__gfx950__)
    unsafeAtomicAdd(p, v);
#else
    atomicAdd(p, v);
#endif
}

__device__ __forceinline__ float bf2f(unsigned int u) {
    union { float f; unsigned int i; } x; x.i = u << 16; return x.f;
}
__device__ __forceinline__ unsigned short f2bf(float f) {
    union { float f; unsigned int u; } x; x.f = f;
    unsigned int r = x.u + 0x7fff + ((x.u >> 16) & 1);
    return (unsigned short)(r >> 16);
}
__device__ __forceinline__ void accum8(float* qa, uint4 u) {
    qa[0] += bf2f(u.x & 0xffff); qa[1] += bf2f(u.x >> 16);
    qa[2] += bf2f(u.y & 0xffff); qa[3] += bf2f(u.y >> 16);
    qa[4] += bf2f(u.z & 0xffff); qa[5] += bf2f(u.z >> 16);
    qa[6] += bf2f(u.w & 0xffff); qa[7] += bf2f(u.w >> 16);
}
__device__ __forceinline__ void pack16(const float* qa, unsigned short* dst) {
    #pragma unroll
    for (int j = 0; j < 2; ++j) {
        uint4 w;
        w.x = ((unsigned int)f2bf(qa[j*8+1]) << 16) | f2bf(qa[j*8+0]);
        w.y = ((unsigned int)f2bf(qa[j*8+3]) << 16) | f2bf(qa[j*8+2]);
        w.z = ((unsigned int)f2bf(qa[j*8+5]) << 16) | f2bf(qa[j*8+4]);
        w.w = ((unsigned int)f2bf(qa[j*8+7]) << 16) | f2bf(qa[j*8+6]);
        ((uint4*)dst)[j] = w;
    }
}

// ---- fused: h1 (blocks 0..391, runs first) + convXW (blocks 392..) ----
__global__ __launch_bounds__(256) void k_h1cx(
    const int* __restrict__ src, const int* __restrict__ dst, const int* __restrict__ rel,
    unsigned char* __restrict__ mark, int* __restrict__ blockHist,
    const float* __restrict__ h, unsigned short* __restrict__ x1,
    const float* __restrict__ W1, const float* __restrict__ Ws1,
    const float* __restrict__ W2, const float* __restrict__ Ws2,
    unsigned short* __restrict__ Wb)
{
    __shared__ int hl[NCOARSE];
    int t = threadIdx.x;
    if (blockIdx.x < NCH) {
        int b = blockIdx.x;
        for (int i = t; i < NCOARSE; i += 256) hl[i] = 0;
        __syncthreads();
        int e0 = b * CHSZ;
        int eend = min(e0 + CHSZ, N_EDGES);
        for (int e = e0 + t; e < eend; e += 256) {
            int d = dst[e];
            mark[rel[e] * SB + src[e]] = 1;
            atomicAdd(&hl[d >> 6], 1);                   // LDS atomic
        }
        __syncthreads();
        for (int i = t; i < NCOARSE; i += 256) blockHist[b * NCOARSE + i] = hl[i];
    } else {
        int id = (blockIdx.x - NCH) * 256 + t;
        if (id < N_PAD * DIM) {
            int v = id >> 7;
            x1[id] = (v < N_NODES) ? f2bf(h[id]) : (unsigned short)0;
        } else {
            int tt = id - N_PAD * DIM;
            int l = tt / 278528, rem = tt % 278528;
            int r = rem >> 14, rr = rem & 16383;
            int n = rr >> 7, k = rr & 127;
            const float* W  = l ? W2 : W1;
            const float* Ws = l ? Ws2 : Ws1;
            float v = (r < 16) ? W[r * 16384 + k * 128 + n] : Ws[k * 128 + n];
            Wb[tt] = f2bf(v);
        }
    }
}

// ---- fused: scanPA (blocks 0..783) + per-bin chunk scan (blocks 784..1565).
// cscan part handles NCH=392 via 2 elems/thread pair scan.
__global__ __launch_bounds__(256) void k_sA(
    const unsigned int* __restrict__ markU, int* __restrict__ partP,
    int* __restrict__ blockHist, int* __restrict__ cOffs)
{
    int t = threadIdx.x;
    if (blockIdx.x < NBLK_PP) {
        __shared__ int red[256];
        int b = blockIdx.x;
        unsigned int u = markU[b * 256 + t];
        red[t] = (int)((u & 1) + ((u >> 8) & 1) + ((u >> 16) & 1) + ((u >> 24) & 1));
        __syncthreads();
        for (int o = 128; o > 0; o >>= 1) {
            if (t < o) red[t] += red[t + o];
            __syncthreads();
        }
        if (t == 0) partP[b] = red[0];
    } else {
        __shared__ int sc[2][256];
        int i = blockIdx.x - NBLK_PP;                    // 0..781
        int j0 = 2 * t, j1 = 2 * t + 1;
        int v0 = (j0 < NCH) ? blockHist[j0 * NCOARSE + i] : 0;
        int v1 = (j1 < NCH) ? blockHist[j1 * NCOARSE + i] : 0;
        int p = v0 + v1;
        sc[0][t] = p; __syncthreads();
        int cur = 0;
        for (int o = 1; o < 256; o <<= 1) {
            sc[cur ^ 1][t] = sc[cur][t] + ((t >= o) ? sc[cur][t - o] : 0);
            __syncthreads();
            cur ^= 1;
        }
        int excl = sc[cur][t] - p;                       // exclusive, no base
        if (j0 < NCH) blockHist[j0 * NCOARSE + i] = excl;
        if (j1 < NCH) blockHist[j1 * NCOARSE + i] = excl + v0;
        if (t == 255) cOffs[i] = sc[cur][255];           // bin total
    }
}

// ---- fused: scanPB (block 0) + cscanB (block 1) ----
__global__ __launch_bounds__(1024) void k_sB(
    const int* __restrict__ partP, int* __restrict__ blkB, int* __restrict__ relB,
    int* __restrict__ cOffs)
{
    int t = threadIdx.x;
    if (blockIdx.x == 0) {
        __shared__ int s1[784], s2[784];
        __shared__ int tot[16], rbase[17];
        int rel = t / 49, pos = t - rel * 49;
        int v = (t < 784) ? partP[t] : 0;
        if (t < 784) s1[t] = v;
        __syncthreads();
        int* cur = s1; int* nxt = s2;
        for (int o = 1; o < 64; o <<= 1) {
            if (t < 784) nxt[t] = cur[t] + ((pos >= o) ? cur[t - o] : 0);
            __syncthreads();
            int* tmp = cur; cur = nxt; nxt = tmp;
        }
        if (t < 784 && pos == 48) tot[rel] = cur[t];
        __syncthreads();
        if (t == 0) {
            int base = 0;
            for (int r = 0; r < 16; ++r) { rbase[r] = base; base += (tot[r] + 63) & ~63; }
            rbase[16] = base;
        }
        __syncthreads();
        if (t < 784) blkB[t] = rbase[rel] + cur[t] - v;
        if (t < 17)  relB[t] = rbase[t];
    } else {
        __shared__ int c1[1024], c2[1024];
        int v = (t < NCOARSE) ? cOffs[t] : 0;
        c1[t] = v; __syncthreads();
        int* cur = c1; int* nxt = c2;
        for (int o = 1; o < 1024; o <<= 1) {
            nxt[t] = cur[t] + ((t >= o) ? cur[t - o] : 0);
            __syncthreads();
            int* tmp = cur; cur = nxt; nxt = tmp;
        }
        if (t < NCOARSE) cOffs[t] = cur[t] - v;          // exclusive base
        if (t == NCOARSE) cOffs[NCOARSE] = cur[NCOARSE - 1];
    }
}

__global__ void k_scanPC(const unsigned int* __restrict__ markU, const int* __restrict__ blkB,
                         int* __restrict__ cidMap, int* __restrict__ srcOf) {
    __shared__ int s1[256], s2[256];
    int b = blockIdx.x, t = threadIdx.x;
    unsigned int u = markU[b * 256 + t];
    int f0 = (int)(u & 1), f1 = (int)((u >> 8) & 1);
    int f2 = (int)((u >> 16) & 1), f3 = (int)((u >> 24) & 1);
    int sum = f0 + f1 + f2 + f3;
    s1[t] = sum; __syncthreads();
    int* cur = s1; int* nxt = s2;
    for (int o = 1; o < 256; o <<= 1) {
        nxt[t] = cur[t] + ((t >= o) ? cur[t - o] : 0);
        __syncthreads();
        int* tmp = cur; cur = nxt; nxt = tmp;
    }
    int cid = blkB[b] + cur[t] - sum;
    int rel = b / 49;
    int key0 = b * 1024 + t * 4;
    int srcBase = key0 - rel * SB;
    if (f0) { cidMap[key0]     = cid; srcOf[cid] = srcBase;     cid++; }
    if (f1) { cidMap[key0 + 1] = cid; srcOf[cid] = srcBase + 1; cid++; }
    if (f2) { cidMap[key0 + 2] = cid; srcOf[cid] = srcBase + 2; cid++; }
    if (f3) { cidMap[key0 + 3] = cid; srcOf[cid] = srcBase + 3; cid++; }
}

// ---- sort pass 1b: scatter to coarse segments (392 blocks now) ----
__global__ __launch_bounds__(256) void k_scat1(
    const int* __restrict__ src, const int* __restrict__ dst, const int* __restrict__ rel,
    const int* __restrict__ cidMap, const int* __restrict__ blockHist,
    const int* __restrict__ cOffs, unsigned int* __restrict__ rtmp)
{
    __shared__ int baseL[NCOARSE];
    __shared__ int hl[NCOARSE];
    int b = blockIdx.x, t = threadIdx.x;
    for (int i = t; i < NCOARSE; i += 256) {
        baseL[i] = blockHist[b * NCOARSE + i] + cOffs[i];
        hl[i] = 0;
    }
    __syncthreads();
    int e0 = b * CHSZ;
    int eend = min(e0 + CHSZ, N_EDGES);
    for (int e = e0 + t; e < eend; e += 256) {
        int d = dst[e];
        int cid = cidMap[rel[e] * SB + src[e]];
        int c = d >> 6;
        int rank = atomicAdd(&hl[c], 1);                 // LDS atomic
        rtmp[baseL[c] + rank] = ((unsigned int)cid << 6) | (unsigned int)(d & 63);
    }
}

// ---- sort pass 2: per coarse bin, final 64-way local sort + offsD ----
__global__ __launch_bounds__(256) void k_p2(
    const unsigned int* __restrict__ rtmp, const int* __restrict__ coarseOffs,
    unsigned int* __restrict__ recs, int* __restrict__ offsD)
{
    __shared__ int cntL[64], exclL[65], cur2[64];
    int i = blockIdx.x, t = threadIdx.x;
    int segB = coarseOffs[i], segE = coarseOffs[i + 1];
    if (t < 64) { cntL[t] = 0; cur2[t] = 0; }
    __syncthreads();
    for (int e = segB + t; e < segE; e += 256)
        atomicAdd(&cntL[rtmp[e] & 63u], 1);
    __syncthreads();
    if (t == 0) {
        int run = segB;
        #pragma unroll
        for (int d = 0; d < 64; ++d) { exclL[d] = run; run += cntL[d]; }
        exclL[64] = run;
    }
    __syncthreads();
    if (t < 64) offsD[i * 64 + t] = exclL[t];
    if (t == 64) offsD[i * 64 + 64] = exclL[64];
    for (int e = segB + t; e < segE; e += 256) {
        unsigned int r = rtmp[e];
        int d = (int)(r & 63u);
        int rank = atomicAdd(&cur2[d], 1);               // LDS atomic
        recs[exclL[d] + rank] = r >> 6;
    }
}

// ---- Phase A: gather-GEMM over compact rows (unchanged) ----
__global__ __launch_bounds__(256) void k_phaseA(
    const unsigned short* __restrict__ x, const unsigned short* __restrict__ Wb,
    const int* __restrict__ srcOf, const int* __restrict__ relB,
    unsigned short* __restrict__ T)
{
    __shared__ __attribute__((aligned(16))) unsigned short Xs[64 * 136];
    __shared__ __attribute__((aligned(16))) unsigned short Cs[64 * 136];
    __shared__ int sRB[17];

    int tid = threadIdx.x;
    if (tid < 17) sRB[tid] = relB[tid];
    __syncthreads();
    int rtot = sRB[16];

    int row = tid >> 2, c0 = tid & 3;

    auto tileInfo = [&](int vb, int& trow0, int& tr) -> bool {
        int chunk = vb / 136;
        int lane = vb - chunk * 136;
        int r = lane >> 3;
        int i = chunk * 8 + (lane & 7);
        int base, cnt;
        if (r == 16) { base = rtot; cnt = N_PAD / 64; }
        else         { base = sRB[r]; cnt = (sRB[r + 1] - base) >> 6; }
        if (i >= cnt) return false;
        trow0 = base + i * 64; tr = r;
        return true;
    };

    int vb = blockIdx.x;
    int cur_row0, cur_r;
    while (vb < NBVIRT && !tileInfo(vb, cur_row0, cur_r)) vb += gridDim.x;
    if (vb >= NBVIRT) return;

    uint4 g0, g1, g2, g3;
    {
        int sr = (cur_r == 16) ? (cur_row0 - rtot + row) : srcOf[cur_row0 + row];
        const uint4* xp = (const uint4*)(x + (size_t)sr * DIM);
        g0 = xp[c0]; g1 = xp[c0 + 4]; g2 = xp[c0 + 8]; g3 = xp[c0 + 12];
    }

    int w = tid >> 6, l = tid & 63;
    int nl = l & 15, q = l >> 4;

    while (true) {
        {
            uint4* lp = (uint4*)(&Xs[row * 136]);
            lp[c0] = g0; lp[c0 + 4] = g1; lp[c0 + 8] = g2; lp[c0 + 12] = g3;
        }
        bf16x8 Bf[2][4];
        {
            const unsigned short* wr = Wb + cur_r * 16384;
            #pragma unroll
            for (int nt = 0; nt < 2; ++nt) {
                int n = w * 32 + nt * 16 + nl;
                #pragma unroll
                for (int kc = 0; kc < 4; ++kc)
                    Bf[nt][kc] = *(const bf16x8*)(wr + n * 128 + kc * 32 + q * 8);
            }
        }
        int nvb = vb + gridDim.x;
        int nxt_row0 = 0, nxt_r = 0;
        while (nvb < NBVIRT && !tileInfo(nvb, nxt_row0, nxt_r)) nvb += gridDim.x;
        bool nhave = (nvb < NBVIRT);
        if (nhave) {
            int sr = (nxt_r == 16) ? (nxt_row0 - rtot + row) : srcOf[nxt_row0 + row];
            const uint4* xp = (const uint4*)(x + (size_t)sr * DIM);
            g0 = xp[c0]; g1 = xp[c0 + 4]; g2 = xp[c0 + 8]; g3 = xp[c0 + 12];
        }
        __syncthreads();
        #pragma unroll
        for (int m = 0; m < 4; ++m) {
            f32x4 a0 = {0.f, 0.f, 0.f, 0.f}, a1 = {0.f, 0.f, 0.f, 0.f};
            #pragma unroll
            for (int kc = 0; kc < 4; ++kc) {
                bf16x8 a = *(const bf16x8*)(&Xs[(m * 16 + nl) * 136 + kc * 32 + q * 8]);
                a0 = __builtin_amdgcn_mfma_f32_16x16x32_bf16(a, Bf[0][kc], a0, 0, 0, 0);
                a1 = __builtin_amdgcn_mfma_f32_16x16x32_bf16(a, Bf[1][kc], a1, 0, 0, 0);
            }
            int colb = w * 32 + nl;
            #pragma unroll
            for (int reg = 0; reg < 4; ++reg) {
                int row2 = m * 16 + q * 4 + reg;
                int sw = ((row2 >> 3) & 1) << 4;
                Cs[row2 * 136 + (colb ^ sw)]        = f2bf(a0[reg]);
                Cs[row2 * 136 + ((colb + 16) ^ sw)] = f2bf(a1[reg]);
            }
        }
        __syncthreads();
        {
            unsigned short* Tb = T + (size_t)cur_row0 * DIM;
            #pragma unroll
            for (int it = 0; it < 4; ++it) {
                int c = tid + it * 256;
                int rw = c >> 4, k8 = c & 15;
                int sw = ((rw >> 3) & 1) << 4;
                uint4 vv = *(const uint4*)(&Cs[rw * 136 + ((k8 * 8) ^ sw)]);
                *(uint4*)(Tb + rw * DIM + k8 * 8) = vv;
            }
        }
        if (!nhave) break;
        vb = nvb; cur_row0 = nxt_row0; cur_r = nxt_r;
    }
}

// ---- Phase B: gather-reduce over T. pool=0: write x2 with relu (layer 1).
// pool=1 (layer 2): relu'd rows staged to f32 LDS tile, segmented-reduced
// per graph, atomically added into hg_sum (k_pool + agg round-trip deleted).
__global__ __launch_bounds__(256) void k_phaseB(
    const unsigned short* __restrict__ T, const unsigned int* __restrict__ recs,
    const int* __restrict__ offsD, const int* __restrict__ relB,
    const float* __restrict__ bias,
    unsigned short* __restrict__ aggOut,
    const int* __restrict__ gids, float* __restrict__ hg_sum, int pool)
{
    __shared__ int sOffs[33];
    __shared__ float sBias[128];
    __shared__ int sSelf;
    __shared__ float Sp[32][129];
    __shared__ int sGid[32];
    int tid = threadIdx.x;
    int v0 = blockIdx.x * 32;
    if (tid < 33) sOffs[tid] = offsD[v0 + tid];
    if (tid == 40) sSelf = relB[16];
    if (tid >= 64 && tid < 96) ((float4*)sBias)[tid - 64] = ((const float4*)bias)[tid - 64];
    if (pool && tid < 32) sGid[tid] = (v0 + tid < N_NODES) ? gids[v0 + tid] : -1;
    __syncthreads();

    int g = tid >> 3, s = tid & 7;
    int dst = v0 + g;
    float qa[16];
    #pragma unroll
    for (int i = 0; i < 16; ++i) qa[i] = sBias[s * 16 + i];

    int beg = sOffs[g], end = sOffs[g + 1];
    int e = beg;
    for (; e + 3 < end; e += 4) {
        unsigned int c0 = recs[e], c1 = recs[e+1], c2 = recs[e+2], c3 = recs[e+3];
        const uint4* t0 = (const uint4*)(T + (size_t)c0 * DIM + s * 16);
        const uint4* t1 = (const uint4*)(T + (size_t)c1 * DIM + s * 16);
        const uint4* t2 = (const uint4*)(T + (size_t)c2 * DIM + s * 16);
        const uint4* t3 = (const uint4*)(T + (size_t)c3 * DIM + s * 16);
        uint4 a0 = t0[0], a1 = t0[1], b0 = t1[0], b1 = t1[1];
        uint4 cc0 = t2[0], cc1 = t2[1], d0 = t3[0], d1 = t3[1];
        accum8(qa, a0); accum8(qa + 8, a1);
        accum8(qa, b0); accum8(qa + 8, b1);
        accum8(qa, cc0); accum8(qa + 8, cc1);
        accum8(qa, d0); accum8(qa + 8, d1);
    }
    for (; e < end; ++e) {
        unsigned int c = recs[e];
        const uint4* tp = (const uint4*)(T + (size_t)c * DIM + s * 16);
        uint4 u0 = tp[0], u1 = tp[1];
        accum8(qa, u0); accum8(qa + 8, u1);
    }
    {
        const uint4* tp = (const uint4*)(T + (size_t)(sSelf + dst) * DIM + s * 16);
        uint4 u0 = tp[0], u1 = tp[1];
        accum8(qa, u0); accum8(qa + 8, u1);
    }

    if (!pool) {
        #pragma unroll
        for (int i = 0; i < 16; ++i) qa[i] = fmaxf(qa[i], 0.f);
        pack16(qa, aggOut + (size_t)dst * DIM + s * 16);
    } else {
        #pragma unroll
        for (int i = 0; i < 16; ++i) Sp[g][s * 16 + i] = fmaxf(qa[i], 0.f);
        __syncthreads();
        // segmented reduce: 128 dims x 2 row-halves
        int d = tid & 127, hh = tid >> 7;
        float run = 0.f; int curg = -2;
        for (int n = hh * 16; n < hh * 16 + 16; ++n) {
            int g2 = sGid[n];
            if (g2 != curg) {
                if (curg >= 0) atomAddF(&hg_sum[curg * DIM + d], run);
                run = 0.f; curg = g2;
            }
            run += Sp[n][d];
        }
        if (curg >= 0) atomAddF(&hg_sum[curg * DIM + d], run);
    }
}

__global__ __launch_bounds__(256) void k_head(
    const float* __restrict__ hg_sum, const int* __restrict__ gids,
    const float* __restrict__ Wfc, const float* __restrict__ bfc,
    const float* __restrict__ Wc, const float* __restrict__ bc,
    float* __restrict__ out)
{
    int g = blockIdx.x, t = threadIdx.x;
    __shared__ float hgl[DIM];
    __shared__ float fcl[FC_DIM];
    __shared__ float lg[N_CLASSES];
    __shared__ int scnt;
    if (t == 0) {
        int lo = 0, hi = N_NODES;
        while (lo < hi) { int mid = (lo + hi) >> 1; if (gids[mid] < g) lo = mid + 1; else hi = mid; }
        int lb = lo;
        hi = N_NODES;
        while (lo < hi) { int mid = (lo + hi) >> 1; if (gids[mid] <= g) lo = mid + 1; else hi = mid; }
        scnt = lo - lb;
    }
    __syncthreads();
    if (t < DIM) {
        float c = (float)max(scnt, 1);
        hgl[t] = hg_sum[g*DIM + t] / c;
    }
    __syncthreads();
    {
        float sv = bfc[t];
        #pragma unroll 4
        for (int k = 0; k < DIM; ++k) sv += hgl[k] * Wfc[k*FC_DIM + t];
        fcl[t] = fmaxf(sv, 0.f);
    }
    __syncthreads();
    if (t < N_CLASSES) {
        float lgt = bc[t];
        #pragma unroll 4
        for (int k = 0; k < FC_DIM; ++k) lgt += fcl[k] * Wc[k*N_CLASSES + t];
        lg[t] = lgt;
    }
    __syncthreads();
    if (t < N_CLASSES) {
        float m = lg[0];
        #pragma unroll
        for (int c = 1; c < N_CLASSES; ++c) m = fmaxf(m, lg[c]);
        float sden = 0.f;
        #pragma unroll
        for (int c = 0; c < N_CLASSES; ++c) sden += expf(lg[c] - m);
        out[g*N_CLASSES + t] = expf(lg[t] - m) / sden;
    }
}

extern "C" void kernel_launch(void* const* d_in, const int* in_sizes, int n_in,
                              void* d_out, int out_size, void* d_ws, size_t ws_size,
                              hipStream_t stream)
{
    const float* h   = (const float*)d_in[0];
    const int*   src = (const int*)d_in[1];
    const int*   dst = (const int*)d_in[2];
    const int*   rel = (const int*)d_in[3];
    const int*   gid = (const int*)d_in[4];
    const float* W1  = (const float*)d_in[5];
    const float* Ws1 = (const float*)d_in[6];
    const float* b1  = (const float*)d_in[7];
    const float* W2  = (const float*)d_in[8];
    const float* Ws2 = (const float*)d_in[9];
    const float* b2  = (const float*)d_in[10];
    const float* Wfc = (const float*)d_in[11];
    const float* bfc = (const float*)d_in[12];
    const float* Wc  = (const float*)d_in[13];
    const float* bc  = (const float*)d_in[14];
    float* out = (float*)d_out;

    char* ws = (char*)d_ws;
    unsigned char* mark = (unsigned char*)(ws + WS_MARK);
    float* hgsum = (float*)(ws + WS_HG);
    int*   srcOf = (int*)(ws + WS_SRCOF);
    int*   blkH  = (int*)(ws + WS_BLKH);
    int*   cOffs = (int*)(ws + WS_COFS);
    int*   partP = (int*)(ws + WS_PARTP);
    int*   blkB  = (int*)(ws + WS_BLKB);
    int*   relB  = (int*)(ws + WS_RELB);
    int*   cidMap= (int*)(ws + WS_CIDMAP);
    unsigned int* rtmp = (unsigned int*)(ws + WS_RTMP);
    unsigned int* recs = (unsigned int*)(ws + WS_RECS);
    int*   offsD = (int*)(ws + WS_OFFSD);
    unsigned short* x1  = (unsigned short*)(ws + WS_X1);
    unsigned short* x2  = (unsigned short*)(ws + WS_X2);
    unsigned short* Wb  = (unsigned short*)(ws + WS_WB);
    unsigned short* T   = (unsigned short*)(ws + WS_T);

    hipMemsetAsync(mark, 0, MEMSET_SZ, stream);    // mark+hg+srcOf

    k_h1cx<<<NCH + NBLK_CX, 256, 0, stream>>>(src, dst, rel, mark, blkH,
                                              h, x1, W1, Ws1, W2, Ws2, Wb);
    k_sA<<<NBLK_PP + NCOARSE, 256, 0, stream>>>((const unsigned int*)mark, partP,
                                                blkH, cOffs);
    k_sB<<<2, 1024, 0, stream>>>(partP, blkB, relB, cOffs);
    k_scanPC<<<NBLK_PP, 256, 0, stream>>>((const unsigned int*)mark, blkB, cidMap, srcOf);

    k_scat1<<<NCH, 256, 0, stream>>>(src, dst, rel, cidMap, blkH, cOffs, rtmp);
    k_p2<<<NCOARSE, 256, 0, stream>>>(rtmp, cOffs, recs, offsD);

    k_phaseA<<<GRID_A, 256, 0, stream>>>(x1, Wb, srcOf, relB, T);
    k_phaseB<<<N_PAD / 32, 256, 0, stream>>>(T, recs, offsD, relB, b1, x2, gid, hgsum, 0);
    k_phaseA<<<GRID_A, 256, 0, stream>>>(x2, Wb + 17 * 16384, srcOf, relB, T);
    k_phaseB<<<N_PAD / 32, 256, 0, stream>>>(T, recs, offsD, relB, b2, x2, gid, hgsum, 1);

    k_head<<<N_GRAPHS, 256, 0, stream>>>(hgsum, gid, Wfc, bfc, Wc, bc, out);
}